// Round 10
// baseline (164.449 us; speedup 1.0000x reference)
//
#include <hip/hip_runtime.h>

#define NBOX 512
#define ENC 6400      // C*ROI*ROI
#define HID 2048
#define DIM 256
#define NCLS 80
#define MEMSZ 1024
#define Bm 16
#define Cc 256
#define Hh 128
#define Ww 128

typedef __attribute__((ext_vector_type(8))) short bf16x8;
typedef __attribute__((ext_vector_type(4))) float f32x4;

__device__ __forceinline__ ushort f2bf(float x) {
  union { float f; unsigned u; } v;
  v.f = x;
  const unsigned r = v.u + 0x7fffu + ((v.u >> 16) & 1u);  // RTNE
  return (ushort)(r >> 16);
}

// ---- blocks 0..N-1: ROI align; block N: class scan; blocks > N: bank copy ----
__global__ __launch_bounds__(256) void roi_scan_copy_kernel(
    const float* __restrict__ rp, const int* __restrict__ bidx,
    const float* __restrict__ bboxes, ushort* __restrict__ feats, int N,
    const int* __restrict__ cls, const int* __restrict__ mcount,
    const float* __restrict__ cfreq, int* __restrict__ pos,
    float* __restrict__ outCNT, float* __restrict__ outCW,
    const float4* __restrict__ csrc, float4* __restrict__ cdst, int cn4) {
  const int n = blockIdx.x;
  if (n > N) {
    // ---- memory-bank copy: 4 independent float4 per thread per round ----
    const int nb = (int)gridDim.x - (N + 1);
    const int cb = n - (N + 1);
    const int base = (cb * 256 + (int)threadIdx.x) * 4;
    const int stride = nb * 256 * 4;
    for (int i = base; i + 3 < cn4; i += stride) {
      const float4 a0 = csrc[i], a1 = csrc[i + 1], a2 = csrc[i + 2], a3 = csrc[i + 3];
      cdst[i] = a0; cdst[i + 1] = a1; cdst[i + 2] = a2; cdst[i + 3] = a3;
    }
    return;
  }
  if (n == N) {
    __shared__ int scls[NBOX];
    __shared__ float sf[NCLS], sc[NCLS];
    __shared__ float s_tot, s_mean;
    const int t = threadIdx.x;
    if (t < 128) *(int4*)&scls[t * 4] = *(const int4*)&cls[t * 4];
    __syncthreads();
    if (t < NCLS) {
      int cnt = 0;
      const int base = mcount[t];
      for (int i = 0; i < N; ++i) {
        if (scls[i] == t) { pos[i] = (base + cnt) % MEMSZ; ++cnt; }
      }
      outCNT[t] = (float)(base + cnt);
      sf[t] = cfreq[t] + (float)cnt;
    }
    __syncthreads();
    if (t == 0) {
      float s = 0.0f;
      for (int i = 0; i < NCLS; ++i) s += sf[i];
      s_tot = s;
    }
    __syncthreads();
    if (t < NCLS) sc[t] = 1.0f / sqrtf(fmaxf(sf[t] / s_tot, 1e-8f) + 1e-8f);
    __syncthreads();
    if (t == 0) {
      float s = 0.0f;
      for (int i = 0; i < NCLS; ++i) s += sc[i];
      s_mean = s / (float)NCLS;
    }
    __syncthreads();
    if (t < NCLS) outCW[t] = sc[t] / s_mean;
    return;
  }
  const int b = bidx[n];
  const float cx = bboxes[n * 4 + 0], cy = bboxes[n * 4 + 1];
  const float bw = bboxes[n * 4 + 2], bh = bboxes[n * 4 + 3];
  const float x1 = cx - bw * 0.5f, y1 = cy - bh * 0.5f;
  const float x2 = cx + bw * 0.5f, y2 = cy + bh * 0.5f;
  const float roi_w = fmaxf(x2 - x1, 1.0f), roi_h = fmaxf(y2 - y1, 1.0f);
  const float stx = roi_w / 5.0f, sty = roi_h / 5.0f;
  for (int j4 = threadIdx.x; j4 < ENC / 4; j4 += 256) {
    ushort4 o;
    float ov[4];
#pragma unroll
    for (int e = 0; e < 4; ++e) {
      const int j = j4 * 4 + e;
      const int c = j / 25, p = j % 25, gy = p / 5, gx = p % 5;
      const float sx = x1 + ((float)gx + 0.5f) * stx;
      const float sy = y1 + ((float)gy + 0.5f) * sty;
      const bool invalid = (sy < -1.0f) || (sy > (float)Hh) || (sx < -1.0f) || (sx > (float)Ww);
      float v = 0.0f;
      if (!invalid) {
        float y = fmaxf(sy, 0.0f), x = fmaxf(sx, 0.0f);
        int yl = (int)floorf(y), xl = (int)floorf(x);
        if (yl >= Hh - 1) y = (float)(Hh - 1);
        if (xl >= Ww - 1) x = (float)(Ww - 1);
        yl = min(yl, Hh - 1);
        xl = min(xl, Ww - 1);
        const int yh = min(yl + 1, Hh - 1), xh = min(xl + 1, Ww - 1);
        const float ly = y - (float)yl, lx = x - (float)xl;
        const float hy = 1.0f - ly, hx = 1.0f - lx;
        const float* base = rp + ((long)(b * Cc + c) << 14);
        const float v00 = base[(yl << 7) + xl];
        const float v01 = base[(yl << 7) + xh];
        const float v10 = base[(yh << 7) + xl];
        const float v11 = base[(yh << 7) + xh];
        v = v00 * hy * hx + v01 * hy * lx + v10 * ly * hx + v11 * ly * lx;
      }
      ov[e] = v;
    }
    o.x = f2bf(ov[0]); o.y = f2bf(ov[1]); o.z = f2bf(ov[2]); o.w = f2bf(ov[3]);
    *(ushort4*)(feats + (long)n * ENC + j4 * 4) = o;
  }
}

// ---- GEMM1 split-K=10: P[z] = feats . w1^T (128x128 tile, swizzled LDS) ----
// r7-verified template. 4 waves (2x2), wave tile 64x64, BK=64, dbuf,
// XOR swizzle chunk^=(row&7). kchunk=640, NT=10. Grid (16,4,10) = 640 blocks.
__global__ __launch_bounds__(256) void gemm1_splitk(
    const ushort* __restrict__ A, const float* __restrict__ B,
    float* __restrict__ P) {
  const int tid = threadIdx.x;
  __shared__ ushort lds[2][16384];  // [A 128x64 | B 128x64] per buffer
  const int lane = tid & 63;
  const int wave = tid >> 6;
  const int wr = wave >> 1, wc = wave & 1;  // 2x2 waves
  const int m0 = blockIdx.y * 128, n0 = blockIdx.x * 128;
  const long kz = (long)blockIdx.z * 640;

  f32x4 acc[4][4];
#pragma unroll
  for (int i = 0; i < 4; ++i)
#pragma unroll
    for (int j = 0; j < 4; ++j) acc[i][j] = (f32x4)0.0f;

  int4 aR[4];
  float4 bR[8];

  auto G_load = [&](int kt) {
#pragma unroll
    for (int p = 0; p < 4; ++p) {
      const int cid = tid + p * 256;
      const int row = cid >> 3, c = cid & 7;
      aR[p] = *(const int4*)(A + (long)(m0 + row) * ENC + kz + kt + c * 8);
      const float* bp = B + (long)(n0 + row) * ENC + kz + kt + c * 8;
      bR[p * 2] = *(const float4*)bp;
      bR[p * 2 + 1] = *(const float4*)(bp + 4);
    }
  };
  auto L_store = [&](int buf) {
    ushort* Ab = &lds[buf][0];
    ushort* Bb = &lds[buf][8192];
#pragma unroll
    for (int p = 0; p < 4; ++p) {
      const int cid = tid + p * 256;
      const int row = cid >> 3, c = (cid & 7) ^ (row & 7);
      *(int4*)&Ab[row * 64 + c * 8] = aR[p];
      ushort4 lo, hi;
      lo.x = f2bf(bR[p * 2].x); lo.y = f2bf(bR[p * 2].y);
      lo.z = f2bf(bR[p * 2].z); lo.w = f2bf(bR[p * 2].w);
      hi.x = f2bf(bR[p * 2 + 1].x); hi.y = f2bf(bR[p * 2 + 1].y);
      hi.z = f2bf(bR[p * 2 + 1].z); hi.w = f2bf(bR[p * 2 + 1].w);
      *(ushort4*)&Bb[row * 64 + c * 8] = lo;
      *(ushort4*)&Bb[row * 64 + c * 8 + 4] = hi;
    }
  };

  const int lr = lane & 15;
  const int g = lane >> 4;
  constexpr int NT = 10;  // kchunk 640 / BK 64

  G_load(0);
  L_store(0);
  __syncthreads();
  for (int t = 0; t < NT; ++t) {
    const int cur = t & 1;
    if (t + 1 < NT) G_load((t + 1) * 64);  // prefetch issues before compute
    const ushort* Ab = &lds[cur][0];
    const ushort* Bb = &lds[cur][8192];
#pragma unroll
    for (int h0 = 0; h0 < 2; ++h0) {
      bf16x8 a[4], b[4];
#pragma unroll
      for (int i = 0; i < 4; ++i) {
        const int row = wr * 64 + i * 16 + lr;
        a[i] = *(const bf16x8*)&Ab[row * 64 + ((h0 * 4 + g) ^ (row & 7)) * 8];
      }
#pragma unroll
      for (int j = 0; j < 4; ++j) {
        const int row = wc * 64 + j * 16 + lr;
        b[j] = *(const bf16x8*)&Bb[row * 64 + ((h0 * 4 + g) ^ (row & 7)) * 8];
      }
#pragma unroll
      for (int i = 0; i < 4; ++i)
#pragma unroll
        for (int j = 0; j < 4; ++j)
          acc[i][j] = __builtin_amdgcn_mfma_f32_16x16x32_bf16(a[i], b[j], acc[i][j], 0, 0, 0);
    }
    if (t + 1 < NT) L_store(cur ^ 1);  // waits on prefetch, fills other buffer
    __syncthreads();
  }

  float* Pp = P + (long)blockIdx.z * NBOX * HID;
  const int r0 = m0 + wr * 64 + ((lane >> 4) << 2);
  const int c0 = n0 + wc * 64 + lr;
#pragma unroll
  for (int i = 0; i < 4; ++i)
#pragma unroll
    for (int j = 0; j < 4; ++j)
#pragma unroll
      for (int r = 0; r < 4; ++r)
        Pp[(long)(r0 + i * 16 + r) * HID + c0 + j * 16] = acc[i][j][r];
}

// ---------------- sum split-K partials + bias + relu -> bf16 ----------------
__global__ __launch_bounds__(256) void reduce_bias_relu_bf16(
    const float* __restrict__ P, const float* __restrict__ bias,
    ushort* __restrict__ out, int MN, int Ncols, int Z) {
  const int e = (blockIdx.x * 256 + threadIdx.x) * 4;
  if (e >= MN) return;
  float4 s = *(const float4*)(P + e);
  for (int z = 1; z < Z; ++z) {
    const float4 t = *(const float4*)(P + (long)z * MN + e);
    s.x += t.x; s.y += t.y; s.z += t.z; s.w += t.w;
  }
  const float4 bb = *(const float4*)(bias + (e & (Ncols - 1)));
  ushort4 o;
  o.x = f2bf(fmaxf(s.x + bb.x, 0.0f));
  o.y = f2bf(fmaxf(s.y + bb.y, 0.0f));
  o.z = f2bf(fmaxf(s.z + bb.z, 0.0f));
  o.w = f2bf(fmaxf(s.w + bb.w, 0.0f));
  *(ushort4*)(out + e) = o;
}

// ---------------- bf16 MFMA NT GEMM (GEMM2), split-K partials ----------------
template <int BM, int BN, int WM, int WN, int TM, int TN>
__global__ __launch_bounds__(WM * WN * 64) void gemm_bf16_nt(
    const ushort* __restrict__ A, const float* __restrict__ B,
    float* __restrict__ P, int M, int N, int K, int kchunk) {
  constexpr int THREADS = WM * WN * 64;
  const int tid = threadIdx.x;
  constexpr int CA = BM * 4 / THREADS;
  constexpr int CB = BN * 8 / THREADS;
  __shared__ ushort As[2][BM][40];
  __shared__ ushort Bs[2][BN][40];
  const int lane = tid & 63;
  const int wave = tid >> 6;
  const int wr = wave / WN, wc = wave % WN;
  const int m0 = blockIdx.y * BM, n0 = blockIdx.x * BN;
  const long kz = (long)blockIdx.z * kchunk;

  f32x4 acc[TM][TN];
#pragma unroll
  for (int i = 0; i < TM; ++i)
#pragma unroll
    for (int j = 0; j < TN; ++j) acc[i][j] = (f32x4)0.0f;

  int4 areg[CA];
  float4 breg[CB];

  auto loadt = [&](int kt) {
#pragma unroll
    for (int i = 0; i < CA; ++i) {
      const int f = tid + i * THREADS;
      areg[i] = *(const int4*)(A + (long)(m0 + (f >> 2)) * K + kz + kt + (f & 3) * 8);
    }
#pragma unroll
    for (int i = 0; i < CB; ++i) {
      const int f = tid + i * THREADS;
      breg[i] = *(const float4*)(B + (long)(n0 + (f >> 3)) * K + kz + kt + (f & 7) * 4);
    }
  };
  auto storet = [&](int buf) {
#pragma unroll
    for (int i = 0; i < CA; ++i) {
      const int f = tid + i * THREADS;
      *(int4*)&As[buf][f >> 2][(f & 3) * 8] = areg[i];
    }
#pragma unroll
    for (int i = 0; i < CB; ++i) {
      const int f = tid + i * THREADS;
      const float4 bv = breg[i];
      ushort4 o;
      o.x = f2bf(bv.x); o.y = f2bf(bv.y); o.z = f2bf(bv.z); o.w = f2bf(bv.w);
      *(ushort4*)&Bs[buf][f >> 3][(f & 7) * 4] = o;
    }
  };

  const int lrow = lane & 15;
  const int kb = (lane >> 4) * 8;
  const int NT = kchunk / 32;

  loadt(0);
  storet(0);
  __syncthreads();
  for (int t = 0; t < NT; ++t) {
    const int cur = t & 1;
    if (t + 1 < NT) loadt((t + 1) * 32);
    bf16x8 a[TM], b[TN];
#pragma unroll
    for (int i = 0; i < TM; ++i)
      a[i] = *(const bf16x8*)&As[cur][wr * (TM * 16) + i * 16 + lrow][kb];
#pragma unroll
    for (int j = 0; j < TN; ++j)
      b[j] = *(const bf16x8*)&Bs[cur][wc * (TN * 16) + j * 16 + lrow][kb];
#pragma unroll
    for (int i = 0; i < TM; ++i)
#pragma unroll
      for (int j = 0; j < TN; ++j)
        acc[i][j] = __builtin_amdgcn_mfma_f32_16x16x32_bf16(a[i], b[j], acc[i][j], 0, 0, 0);
    if (t + 1 < NT) storet(cur ^ 1);
    __syncthreads();
  }

  float* Pp = P + (long)blockIdx.z * M * N;
  const int r0 = m0 + wr * (TM * 16) + ((lane >> 4) << 2);
  const int c0 = n0 + wc * (TN * 16) + lrow;
#pragma unroll
  for (int i = 0; i < TM; ++i)
#pragma unroll
    for (int j = 0; j < TN; ++j)
#pragma unroll
      for (int r = 0; r < 4; ++r)
        Pp[(long)(r0 + i * 16 + r) * N + c0 + j * 16] = acc[i][j][r];
}

// ---------------- GEMM2 partials + bias + 1e-8, L2-normalize, write outFN + scatter ----------------
__global__ __launch_bounds__(256) void reduce_norm_scatter(
    const float* __restrict__ P, const float* __restrict__ b2,
    float* __restrict__ outFN, float* __restrict__ outMB,
    const int* __restrict__ cls, const int* __restrict__ pos, int M, int Z) {
  const int m = blockIdx.x, d = threadIdx.x;  // DIM==256 threads
  float f = 0.0f;
  for (int z = 0; z < Z; ++z) f += P[((long)z * M + m) * DIM + d];
  f += b2[d] + 1e-8f;
  float ss = f * f;
#pragma unroll
  for (int o = 32; o > 0; o >>= 1) ss += __shfl_xor(ss, o, 64);
  __shared__ float sred[4];
  if ((d & 63) == 0) sred[d >> 6] = ss;
  __syncthreads();
  const float tot = sred[0] + sred[1] + sred[2] + sred[3];
  const float nrm = fmaxf(sqrtf(tot), 1e-12f);
  const float r = f / nrm;
  outFN[(long)m * DIM + d] = r;
  outMB[((long)cls[m] * MEMSZ + pos[m]) * DIM + d] = r;
}

// ---------------- launch ----------------
extern "C" void kernel_launch(void* const* d_in, const int* in_sizes, int n_in,
                              void* d_out, int out_size, void* d_ws, size_t ws_size,
                              hipStream_t stream) {
  const float* rp = (const float*)d_in[0];
  const int* bidx = (const int*)d_in[1];
  const int* cls = (const int*)d_in[2];
  const float* bboxes = (const float*)d_in[3];
  const float* w1 = (const float*)d_in[6];
  const float* b1 = (const float*)d_in[7];
  const float* w2 = (const float*)d_in[8];
  const float* b2 = (const float*)d_in[9];
  const float* mbank = (const float*)d_in[10];
  const int* mcount = (const int*)d_in[11];
  const float* cfreq = (const float*)d_in[12];
  const int N = in_sizes[1];  // 512

  // workspace layout (bytes, all 16B-aligned)
  char* ws = (char*)d_ws;
  ushort* feats = (ushort*)ws;                         // 6,553,600 B
  float* P1 = (float*)(ws + 6553600);                  // 10*512*2048*4 = 41,943,040 B
  ushort* h = (ushort*)(ws + 6553600 + 41943040);      // 2,097,152 B
  int* pos = (int*)(ws + 6553600 + 41943040 + 2097152);
  float* P2 = P1;  // alias (P1 consumed by K3 before gemm2 writes)

  // output layout (floats)
  float* outFN = (float*)d_out;              // 512*256
  float* outMB = outFN + (long)NBOX * DIM;   // 80*1024*256
  float* outCNT = outMB + (long)NCLS * MEMSZ * DIM;
  float* outCW = outCNT + NCLS;

  // K1: ROI align (0..N-1) + class scan (N) + memory-bank copy (N+1 .. N+1536)
  roi_scan_copy_kernel<<<N + 1 + 1536, 256, 0, stream>>>(
      rp, bidx, bboxes, feats, N, cls, mcount, cfreq, pos, outCNT, outCW,
      (const float4*)mbank, (float4*)outMB, NCLS * MEMSZ * DIM / 4);

  // K2: GEMM1 split-K=10, grid (16,4,10) = 640 blocks (2+ blocks/CU).
  gemm1_splitk<<<dim3(HID / 128, NBOX / 128, 10), 256, 0, stream>>>(feats, w1, P1);

  // K3: sum 10 partials + bias + relu -> h (bf16)
  reduce_bias_relu_bf16<<<NBOX * HID / 4 / 256, 256, 0, stream>>>(
      P1, b1, h, NBOX * HID, HID, 10);

  // K4: GEMM2 (512,2048)bf16 x (256,2048)fp32^T, BN=32, split-K=8 -> 256 blocks
  gemm_bf16_nt<128, 32, 2, 2, 4, 1><<<dim3(DIM / 32, NBOX / 128, 8), 256, 0, stream>>>(
      h, w2, P2, NBOX, DIM, HID, HID / 8);

  // K5: reduce + bias + normalize + write feat_norm + scatter into bank
  reduce_norm_scatter<<<NBOX, 256, 0, stream>>>(P2, b2, outFN, outMB, cls, pos, NBOX, 8);
}

// Round 11
// 127.358 us; speedup vs baseline: 1.2912x; 1.2912x over previous
//
#include <hip/hip_runtime.h>

#define NBOX 512
#define ENC 6400      // C*ROI*ROI
#define HID 2048
#define DIM 256
#define NCLS 80
#define MEMSZ 1024
#define Bm 16
#define Cc 256
#define Hh 128
#define Ww 128

typedef __attribute__((ext_vector_type(8))) short bf16x8;
typedef __attribute__((ext_vector_type(4))) float f32x4;

__device__ __forceinline__ ushort f2bf(float x) {
  union { float f; unsigned u; } v;
  v.f = x;
  const unsigned r = v.u + 0x7fffu + ((v.u >> 16) & 1u);  // RTNE
  return (ushort)(r >> 16);
}

// ---- blocks 0..N-1: ROI align; block N: class scan ----
__global__ __launch_bounds__(256) void roi_scan_kernel(
    const float* __restrict__ rp, const int* __restrict__ bidx,
    const float* __restrict__ bboxes, ushort* __restrict__ feats, int N,
    const int* __restrict__ cls, const int* __restrict__ mcount,
    const float* __restrict__ cfreq, int* __restrict__ pos,
    float* __restrict__ outCNT, float* __restrict__ outCW) {
  const int n = blockIdx.x;
  if (n == N) {
    __shared__ int scls[NBOX];
    __shared__ float sf[NCLS], sc[NCLS];
    __shared__ float s_tot, s_mean;
    const int t = threadIdx.x;
    if (t < 128) *(int4*)&scls[t * 4] = *(const int4*)&cls[t * 4];
    __syncthreads();
    if (t < NCLS) {
      int cnt = 0;
      const int base = mcount[t];
      for (int i = 0; i < N; ++i) {
        if (scls[i] == t) { pos[i] = (base + cnt) % MEMSZ; ++cnt; }
      }
      outCNT[t] = (float)(base + cnt);
      sf[t] = cfreq[t] + (float)cnt;
    }
    __syncthreads();
    if (t == 0) {
      float s = 0.0f;
      for (int i = 0; i < NCLS; ++i) s += sf[i];
      s_tot = s;
    }
    __syncthreads();
    if (t < NCLS) sc[t] = 1.0f / sqrtf(fmaxf(sf[t] / s_tot, 1e-8f) + 1e-8f);
    __syncthreads();
    if (t == 0) {
      float s = 0.0f;
      for (int i = 0; i < NCLS; ++i) s += sc[i];
      s_mean = s / (float)NCLS;
    }
    __syncthreads();
    if (t < NCLS) outCW[t] = sc[t] / s_mean;
    return;
  }
  const int b = bidx[n];
  const float cx = bboxes[n * 4 + 0], cy = bboxes[n * 4 + 1];
  const float bw = bboxes[n * 4 + 2], bh = bboxes[n * 4 + 3];
  const float x1 = cx - bw * 0.5f, y1 = cy - bh * 0.5f;
  const float x2 = cx + bw * 0.5f, y2 = cy + bh * 0.5f;
  const float roi_w = fmaxf(x2 - x1, 1.0f), roi_h = fmaxf(y2 - y1, 1.0f);
  const float stx = roi_w / 5.0f, sty = roi_h / 5.0f;
  for (int j4 = threadIdx.x; j4 < ENC / 4; j4 += 256) {
    ushort4 o;
    float ov[4];
#pragma unroll
    for (int e = 0; e < 4; ++e) {
      const int j = j4 * 4 + e;
      const int c = j / 25, p = j % 25, gy = p / 5, gx = p % 5;
      const float sx = x1 + ((float)gx + 0.5f) * stx;
      const float sy = y1 + ((float)gy + 0.5f) * sty;
      const bool invalid = (sy < -1.0f) || (sy > (float)Hh) || (sx < -1.0f) || (sx > (float)Ww);
      float v = 0.0f;
      if (!invalid) {
        float y = fmaxf(sy, 0.0f), x = fmaxf(sx, 0.0f);
        int yl = (int)floorf(y), xl = (int)floorf(x);
        if (yl >= Hh - 1) y = (float)(Hh - 1);
        if (xl >= Ww - 1) x = (float)(Ww - 1);
        yl = min(yl, Hh - 1);
        xl = min(xl, Ww - 1);
        const int yh = min(yl + 1, Hh - 1), xh = min(xl + 1, Ww - 1);
        const float ly = y - (float)yl, lx = x - (float)xl;
        const float hy = 1.0f - ly, hx = 1.0f - lx;
        const float* base = rp + ((long)(b * Cc + c) << 14);
        const float v00 = base[(yl << 7) + xl];
        const float v01 = base[(yl << 7) + xh];
        const float v10 = base[(yh << 7) + xl];
        const float v11 = base[(yh << 7) + xh];
        v = v00 * hy * hx + v01 * hy * lx + v10 * ly * hx + v11 * ly * lx;
      }
      ov[e] = v;
    }
    o.x = f2bf(ov[0]); o.y = f2bf(ov[1]); o.z = f2bf(ov[2]); o.w = f2bf(ov[3]);
    *(ushort4*)(feats + (long)n * ENC + j4 * 4) = o;
  }
}

// ---- GEMM1 split-K=5 (r7-verified template) + fused bank-copy blocks ----
// z in [0,5): gemm 128x128 tile, 4 waves (2x2), wave tile 64x64, BK=64, dbuf,
// XOR swizzle chunk^=(row&7), kchunk=1280, NT=20. 320 gemm blocks.
// z in [5,13): 512 copy blocks, 4-deep float4 stream (same 32 KB LDS footprint).
__global__ __launch_bounds__(256) void gemm1_splitk(
    const ushort* __restrict__ A, const float* __restrict__ B,
    float* __restrict__ P,
    const float4* __restrict__ csrc, float4* __restrict__ cdst, int cn4) {
  const int tid = threadIdx.x;
  constexpr int ZG = 5;
  if ((int)blockIdx.z >= ZG) {
    // ---- memory-bank copy: 512 blocks, 4 independent float4 per round ----
    const int nb = 64 * ((int)gridDim.z - ZG);
    const int cb = (((int)blockIdx.z - ZG) * 4 + (int)blockIdx.y) * 16 + (int)blockIdx.x;
    const int base = (cb * 256 + tid) * 4;
    const int stride = nb * 256 * 4;
    for (int i = base; i + 3 < cn4; i += stride) {
      const float4 a0 = csrc[i], a1 = csrc[i + 1], a2 = csrc[i + 2], a3 = csrc[i + 3];
      cdst[i] = a0; cdst[i + 1] = a1; cdst[i + 2] = a2; cdst[i + 3] = a3;
    }
    return;
  }
  __shared__ ushort lds[2][16384];  // [A 128x64 | B 128x64] per buffer (32 KB)
  const int lane = tid & 63;
  const int wave = tid >> 6;
  const int wr = wave >> 1, wc = wave & 1;  // 2x2 waves
  const int m0 = blockIdx.y * 128, n0 = blockIdx.x * 128;
  const long kz = (long)blockIdx.z * 1280;

  f32x4 acc[4][4];
#pragma unroll
  for (int i = 0; i < 4; ++i)
#pragma unroll
    for (int j = 0; j < 4; ++j) acc[i][j] = (f32x4)0.0f;

  int4 aR[4];
  float4 bR[8];

  auto G_load = [&](int kt) {
#pragma unroll
    for (int p = 0; p < 4; ++p) {
      const int cid = tid + p * 256;
      const int row = cid >> 3, c = cid & 7;
      aR[p] = *(const int4*)(A + (long)(m0 + row) * ENC + kz + kt + c * 8);
      const float* bp = B + (long)(n0 + row) * ENC + kz + kt + c * 8;
      bR[p * 2] = *(const float4*)bp;
      bR[p * 2 + 1] = *(const float4*)(bp + 4);
    }
  };
  auto L_store = [&](int buf) {
    ushort* Ab = &lds[buf][0];
    ushort* Bb = &lds[buf][8192];
#pragma unroll
    for (int p = 0; p < 4; ++p) {
      const int cid = tid + p * 256;
      const int row = cid >> 3, c = (cid & 7) ^ (row & 7);
      *(int4*)&Ab[row * 64 + c * 8] = aR[p];
      ushort4 lo, hi;
      lo.x = f2bf(bR[p * 2].x); lo.y = f2bf(bR[p * 2].y);
      lo.z = f2bf(bR[p * 2].z); lo.w = f2bf(bR[p * 2].w);
      hi.x = f2bf(bR[p * 2 + 1].x); hi.y = f2bf(bR[p * 2 + 1].y);
      hi.z = f2bf(bR[p * 2 + 1].z); hi.w = f2bf(bR[p * 2 + 1].w);
      *(ushort4*)&Bb[row * 64 + c * 8] = lo;
      *(ushort4*)&Bb[row * 64 + c * 8 + 4] = hi;
    }
  };

  const int lr = lane & 15;
  const int g = lane >> 4;
  constexpr int NT = 20;  // kchunk 1280 / BK 64

  G_load(0);
  L_store(0);
  __syncthreads();
  for (int t = 0; t < NT; ++t) {
    const int cur = t & 1;
    if (t + 1 < NT) G_load((t + 1) * 64);  // prefetch issues before compute
    const ushort* Ab = &lds[cur][0];
    const ushort* Bb = &lds[cur][8192];
#pragma unroll
    for (int h0 = 0; h0 < 2; ++h0) {
      bf16x8 a[4], b[4];
#pragma unroll
      for (int i = 0; i < 4; ++i) {
        const int row = wr * 64 + i * 16 + lr;
        a[i] = *(const bf16x8*)&Ab[row * 64 + ((h0 * 4 + g) ^ (row & 7)) * 8];
      }
#pragma unroll
      for (int j = 0; j < 4; ++j) {
        const int row = wc * 64 + j * 16 + lr;
        b[j] = *(const bf16x8*)&Bb[row * 64 + ((h0 * 4 + g) ^ (row & 7)) * 8];
      }
#pragma unroll
      for (int i = 0; i < 4; ++i)
#pragma unroll
        for (int j = 0; j < 4; ++j)
          acc[i][j] = __builtin_amdgcn_mfma_f32_16x16x32_bf16(a[i], b[j], acc[i][j], 0, 0, 0);
    }
    if (t + 1 < NT) L_store(cur ^ 1);  // waits on prefetch, fills other buffer
    __syncthreads();
  }

  float* Pp = P + (long)blockIdx.z * NBOX * HID;
  const int r0 = m0 + wr * 64 + ((lane >> 4) << 2);
  const int c0 = n0 + wc * 64 + lr;
#pragma unroll
  for (int i = 0; i < 4; ++i)
#pragma unroll
    for (int j = 0; j < 4; ++j)
#pragma unroll
      for (int r = 0; r < 4; ++r)
        Pp[(long)(r0 + i * 16 + r) * HID + c0 + j * 16] = acc[i][j][r];
}

// ---------------- sum split-K partials + bias + relu -> bf16 ----------------
__global__ __launch_bounds__(256) void reduce_bias_relu_bf16(
    const float* __restrict__ P, const float* __restrict__ bias,
    ushort* __restrict__ out, int MN, int Ncols, int Z) {
  const int e = (blockIdx.x * 256 + threadIdx.x) * 4;
  if (e >= MN) return;
  float4 s = *(const float4*)(P + e);
  for (int z = 1; z < Z; ++z) {
    const float4 t = *(const float4*)(P + (long)z * MN + e);
    s.x += t.x; s.y += t.y; s.z += t.z; s.w += t.w;
  }
  const float4 bb = *(const float4*)(bias + (e & (Ncols - 1)));
  ushort4 o;
  o.x = f2bf(fmaxf(s.x + bb.x, 0.0f));
  o.y = f2bf(fmaxf(s.y + bb.y, 0.0f));
  o.z = f2bf(fmaxf(s.z + bb.z, 0.0f));
  o.w = f2bf(fmaxf(s.w + bb.w, 0.0f));
  *(ushort4*)(out + e) = o;
}

// ---------------- bf16 MFMA NT GEMM (GEMM2), split-K partials ----------------
template <int BM, int BN, int WM, int WN, int TM, int TN>
__global__ __launch_bounds__(WM * WN * 64) void gemm_bf16_nt(
    const ushort* __restrict__ A, const float* __restrict__ B,
    float* __restrict__ P, int M, int N, int K, int kchunk) {
  constexpr int THREADS = WM * WN * 64;
  const int tid = threadIdx.x;
  constexpr int CA = BM * 4 / THREADS;
  constexpr int CB = BN * 8 / THREADS;
  __shared__ ushort As[2][BM][40];
  __shared__ ushort Bs[2][BN][40];
  const int lane = tid & 63;
  const int wave = tid >> 6;
  const int wr = wave / WN, wc = wave % WN;
  const int m0 = blockIdx.y * BM, n0 = blockIdx.x * BN;
  const long kz = (long)blockIdx.z * kchunk;

  f32x4 acc[TM][TN];
#pragma unroll
  for (int i = 0; i < TM; ++i)
#pragma unroll
    for (int j = 0; j < TN; ++j) acc[i][j] = (f32x4)0.0f;

  int4 areg[CA];
  float4 breg[CB];

  auto loadt = [&](int kt) {
#pragma unroll
    for (int i = 0; i < CA; ++i) {
      const int f = tid + i * THREADS;
      areg[i] = *(const int4*)(A + (long)(m0 + (f >> 2)) * K + kz + kt + (f & 3) * 8);
    }
#pragma unroll
    for (int i = 0; i < CB; ++i) {
      const int f = tid + i * THREADS;
      breg[i] = *(const float4*)(B + (long)(n0 + (f >> 3)) * K + kz + kt + (f & 7) * 4);
    }
  };
  auto storet = [&](int buf) {
#pragma unroll
    for (int i = 0; i < CA; ++i) {
      const int f = tid + i * THREADS;
      *(int4*)&As[buf][f >> 2][(f & 3) * 8] = areg[i];
    }
#pragma unroll
    for (int i = 0; i < CB; ++i) {
      const int f = tid + i * THREADS;
      const float4 bv = breg[i];
      ushort4 o;
      o.x = f2bf(bv.x); o.y = f2bf(bv.y); o.z = f2bf(bv.z); o.w = f2bf(bv.w);
      *(ushort4*)&Bs[buf][f >> 3][(f & 7) * 4] = o;
    }
  };

  const int lrow = lane & 15;
  const int kb = (lane >> 4) * 8;
  const int NT = kchunk / 32;

  loadt(0);
  storet(0);
  __syncthreads();
  for (int t = 0; t < NT; ++t) {
    const int cur = t & 1;
    if (t + 1 < NT) loadt((t + 1) * 32);
    bf16x8 a[TM], b[TN];
#pragma unroll
    for (int i = 0; i < TM; ++i)
      a[i] = *(const bf16x8*)&As[cur][wr * (TM * 16) + i * 16 + lrow][kb];
#pragma unroll
    for (int j = 0; j < TN; ++j)
      b[j] = *(const bf16x8*)&Bs[cur][wc * (TN * 16) + j * 16 + lrow][kb];
#pragma unroll
    for (int i = 0; i < TM; ++i)
#pragma unroll
      for (int j = 0; j < TN; ++j)
        acc[i][j] = __builtin_amdgcn_mfma_f32_16x16x32_bf16(a[i], b[j], acc[i][j], 0, 0, 0);
    if (t + 1 < NT) storet(cur ^ 1);
    __syncthreads();
  }

  float* Pp = P + (long)blockIdx.z * M * N;
  const int r0 = m0 + wr * (TM * 16) + ((lane >> 4) << 2);
  const int c0 = n0 + wc * (TN * 16) + lrow;
#pragma unroll
  for (int i = 0; i < TM; ++i)
#pragma unroll
    for (int j = 0; j < TN; ++j)
#pragma unroll
      for (int r = 0; r < 4; ++r)
        Pp[(long)(r0 + i * 16 + r) * N + c0 + j * 16] = acc[i][j][r];
}

// ---------------- GEMM2 partials + bias + 1e-8, L2-normalize, write outFN + scatter ----------------
__global__ __launch_bounds__(256) void reduce_norm_scatter(
    const float* __restrict__ P, const float* __restrict__ b2,
    float* __restrict__ outFN, float* __restrict__ outMB,
    const int* __restrict__ cls, const int* __restrict__ pos, int M, int Z) {
  const int m = blockIdx.x, d = threadIdx.x;  // DIM==256 threads
  float f = 0.0f;
  for (int z = 0; z < Z; ++z) f += P[((long)z * M + m) * DIM + d];
  f += b2[d] + 1e-8f;
  float ss = f * f;
#pragma unroll
  for (int o = 32; o > 0; o >>= 1) ss += __shfl_xor(ss, o, 64);
  __shared__ float sred[4];
  if ((d & 63) == 0) sred[d >> 6] = ss;
  __syncthreads();
  const float tot = sred[0] + sred[1] + sred[2] + sred[3];
  const float nrm = fmaxf(sqrtf(tot), 1e-12f);
  const float r = f / nrm;
  outFN[(long)m * DIM + d] = r;
  outMB[((long)cls[m] * MEMSZ + pos[m]) * DIM + d] = r;
}

// ---------------- launch ----------------
extern "C" void kernel_launch(void* const* d_in, const int* in_sizes, int n_in,
                              void* d_out, int out_size, void* d_ws, size_t ws_size,
                              hipStream_t stream) {
  const float* rp = (const float*)d_in[0];
  const int* bidx = (const int*)d_in[1];
  const int* cls = (const int*)d_in[2];
  const float* bboxes = (const float*)d_in[3];
  const float* w1 = (const float*)d_in[6];
  const float* b1 = (const float*)d_in[7];
  const float* w2 = (const float*)d_in[8];
  const float* b2 = (const float*)d_in[9];
  const float* mbank = (const float*)d_in[10];
  const int* mcount = (const int*)d_in[11];
  const float* cfreq = (const float*)d_in[12];
  const int N = in_sizes[1];  // 512

  // workspace layout (bytes, all 16B-aligned)
  char* ws = (char*)d_ws;
  ushort* feats = (ushort*)ws;                        // 6,553,600 B
  float* P1 = (float*)(ws + 6553600);                 // 5*512*2048*4 = 20,971,520 B
  ushort* h = (ushort*)(ws + 6553600 + 20971520);     // 2,097,152 B
  int* pos = (int*)(ws + 6553600 + 20971520 + 2097152);
  float* P2 = P1;  // alias (P1 consumed by K3 before gemm2 writes)

  // output layout (floats)
  float* outFN = (float*)d_out;              // 512*256
  float* outMB = outFN + (long)NBOX * DIM;   // 80*1024*256
  float* outCNT = outMB + (long)NCLS * MEMSZ * DIM;
  float* outCW = outCNT + NCLS;

  // K1: ROI align + class scan only (copy moved into K2 for overlap)
  roi_scan_kernel<<<N + 1, 256, 0, stream>>>(rp, bidx, bboxes, feats, N,
                                             cls, mcount, cfreq, pos, outCNT, outCW);

  // K2: GEMM1 split-K=5 (z=0..4, 320 blocks) + bank copy (z=5..12, 512 blocks)
  gemm1_splitk<<<dim3(HID / 128, NBOX / 128, 13), 256, 0, stream>>>(
      feats, w1, P1, (const float4*)mbank, (float4*)outMB, NCLS * MEMSZ * DIM / 4);

  // K3: sum 5 partials + bias + relu -> h (bf16)
  reduce_bias_relu_bf16<<<NBOX * HID / 4 / 256, 256, 0, stream>>>(
      P1, b1, h, NBOX * HID, HID, 5);

  // K4: GEMM2 (512,2048)bf16 x (256,2048)fp32^T, split-K=8, 128 blocks (r7 config)
  gemm_bf16_nt<128, 64, 2, 2, 4, 2><<<dim3(DIM / 64, NBOX / 128, 8), 256, 0, stream>>>(
      h, w2, P2, NBOX, DIM, HID, HID / 8);

  // K5: reduce + bias + normalize + write feat_norm + scatter into bank
  reduce_norm_scatter<<<NBOX, 256, 0, stream>>>(P2, b2, outFN, outMB, cls, pos, NBOX, 8);
}